// Round 13
// baseline (104.884 us; speedup 1.0000x reference)
//
#include <hip/hip_runtime.h>
#include <hip/hip_bf16.h>

// NeuralAdditiveModel: out[b] = sum_f( W3[f] . relu(W2[f]^T relu(x[b,f]*W1[f]+b1[f]) + b2[f]) + b3[f] ) + bias
// B=8192, F=128, S=128, H1=64, O=1
#define B_ 8192
#define F_ 128
#define S_ 128
#define H_ 64
#define NCHUNK 8                      // b-chunks per feature; grid = F_*NCHUNK = 1024

typedef __attribute__((ext_vector_type(4))) float f32x4;
typedef __attribute__((ext_vector_type(8))) short bf16x8;  // 8 bf16 in 4 VGPRs

static __device__ __forceinline__ short f2bf(float v) {
    __hip_bfloat16 t = __float2bfloat16(v);   // RNE
    return __builtin_bit_cast(short, t);
}

// ---- Main: persistent-A, NO ATOMICS. Block = (f, 1024-row b-chunk); wave = 256 rows
// (8 iters x 32). W2[f] converted to bf16 A-frags in-register ONCE per block (replaces
// the prep dispatch). Per-(f,b) result written non-atomically to part[f][b] (each
// element written exactly once -> full-BW coalesced stores, no init kernel needed).
__global__ __launch_bounds__(256, 2) void nam_main(
    const float* __restrict__ x,    // [B,F]
    const float* __restrict__ W1,   // [F,S]
    const float* __restrict__ b1,   // [F,S]
    const float* __restrict__ W2,   // [F,S,H]
    const float* __restrict__ b2,   // [F,H]
    const float* __restrict__ W3,   // [F,H] (O=1)
    const float* __restrict__ b3,   // [F]
    float* __restrict__ part)       // [F,B] partials in d_ws
{
    const int f     = blockIdx.x >> 3;      // 8 consecutive blocks share f
    const int chunk = blockIdx.x & 7;
    const int tid   = threadIdx.x;
    const int w     = tid >> 6;
    const int l     = tid & 63;
    const int l16   = l & 15;
    const int lg    = l >> 4;

    const int b0 = chunk * (B_ / NCHUNK) + w * 256;   // this wave's 256 b-rows

    // ---- one-time A-frag build: W2^T[h=m*16+l16][s=kk*32+lg*8+j] -> bf16, in VGPRs ----
    const float* __restrict__ W2f = W2 + (size_t)f * S_ * H_;
    bf16x8 afrag[16];                                  // 64 VGPR
#pragma unroll
    for (int kk = 0; kk < 4; ++kk) {
#pragma unroll
        for (int m = 0; m < 4; ++m) {
            const float* __restrict__ src =
                W2f + (size_t)(kk * 32 + lg * 8) * H_ + m * 16 + l16;
            bf16x8 v;
#pragma unroll
            for (int j = 0; j < 8; ++j) v[j] = f2bf(src[j * H_]);
            afrag[kk * 4 + m] = v;
        }
    }

    // ---- one-time register-resident small weights ----
    const float* __restrict__ W1f = W1 + f * S_;
    const float* __restrict__ b1f = b1 + f * S_;
    f32x4 w1r[8], b1r[8];                              // 64 VGPR (s = kk*32+lg*8+j)
#pragma unroll
    for (int kk = 0; kk < 4; ++kk) {
        w1r[kk * 2]     = *(const f32x4*)(W1f + kk * 32 + lg * 8);
        w1r[kk * 2 + 1] = *(const f32x4*)(W1f + kk * 32 + lg * 8 + 4);
        b1r[kk * 2]     = *(const f32x4*)(b1f + kk * 32 + lg * 8);
        b1r[kk * 2 + 1] = *(const f32x4*)(b1f + kk * 32 + lg * 8 + 4);
    }
    const float* __restrict__ b2f = b2 + f * H_;
    const float* __restrict__ W3f = W3 + f * H_;
    f32x4 b2v[4], w3v[4];                              // 32 VGPR (h = m*16+lg*4+r)
#pragma unroll
    for (int m = 0; m < 4; ++m) {
        b2v[m] = *(const f32x4*)(b2f + m * 16 + lg * 4);
        w3v[m] = *(const f32x4*)(W3f + m * 16 + lg * 4);
    }
    const float b3f = b3[f];

    // x[b][f]: strided per-lane dword (16 lines per load; L1-served, r8-proven fine)
    const float* __restrict__ xb = x + f;
    float* __restrict__ pf = part + (size_t)f * B_;

    float xv0 = xb[(size_t)(b0 + l16) * F_];
    float xv1 = xb[(size_t)(b0 + 16 + l16) * F_];

#pragma unroll 1
    for (int it = 0; it < 8; ++it) {
        const int bbase = b0 + it * 32;
        float nx0 = 0.f, nx1 = 0.f;
        if (it < 7) {                                   // prefetch next iter's x
            nx0 = xb[(size_t)(bbase + 32 + l16) * F_];
            nx1 = xb[(size_t)(bbase + 48 + l16) * F_];
        }

        f32x4 acc[4][2];
#pragma unroll
        for (int m = 0; m < 4; ++m) {
            acc[m][0] = (f32x4){0.f, 0.f, 0.f, 0.f};
            acc[m][1] = (f32x4){0.f, 0.f, 0.f, 0.f};
        }

#pragma unroll
        for (int kk = 0; kk < 4; ++kk) {
            bf16x8 bf0, bf1;                            // h1^T in bf16
#pragma unroll
            for (int j = 0; j < 4; ++j) {
                bf0[j]     = f2bf(fmaxf(fmaf(xv0, w1r[kk*2][j],   b1r[kk*2][j]),   0.f));
                bf0[j + 4] = f2bf(fmaxf(fmaf(xv0, w1r[kk*2+1][j], b1r[kk*2+1][j]), 0.f));
                bf1[j]     = f2bf(fmaxf(fmaf(xv1, w1r[kk*2][j],   b1r[kk*2][j]),   0.f));
                bf1[j + 4] = f2bf(fmaxf(fmaf(xv1, w1r[kk*2+1][j], b1r[kk*2+1][j]), 0.f));
            }
#pragma unroll
            for (int m = 0; m < 4; ++m) {
                acc[m][0] = __builtin_amdgcn_mfma_f32_16x16x32_bf16(afrag[kk*4+m], bf0, acc[m][0], 0, 0, 0);
                acc[m][1] = __builtin_amdgcn_mfma_f32_16x16x32_bf16(afrag[kk*4+m], bf1, acc[m][1], 0, 0, 0);
            }
        }

        // epilogue: fo[b] = sum_h relu(h2+b2)*W3 (+b3); lane h = m*16+lg*4+r
        float fo0 = 0.f, fo1 = 0.f;
#pragma unroll
        for (int m = 0; m < 4; ++m) {
#pragma unroll
            for (int r = 0; r < 4; ++r) {
                fo0 = fmaf(fmaxf(acc[m][0][r] + b2v[m][r], 0.f), w3v[m][r], fo0);
                fo1 = fmaf(fmaxf(acc[m][1][r] + b2v[m][r], 0.f), w3v[m][r], fo1);
            }
        }
        fo0 += __shfl_xor(fo0, 16);
        fo0 += __shfl_xor(fo0, 32);
        fo1 += __shfl_xor(fo1, 16);
        fo1 += __shfl_xor(fo1, 32);
        if (lg == 0) {                                  // plain coalesced stores, no atomics
            pf[bbase + l16]      = fo0 + b3f;
            pf[bbase + 16 + l16] = fo1 + b3f;
        }
        xv0 = nx0;
        xv1 = nx1;
    }
}

// ---- Reduce: out[b] = bias[0] + sum_f part[f][b]. 4 MB coalesced reads. ----
__global__ __launch_bounds__(256) void nam_reduce(const float* __restrict__ part,
                                                  const float* __restrict__ bias,
                                                  float* __restrict__ out) {
    const int b = blockIdx.x * 256 + threadIdx.x;
    float s0 = 0.f, s1 = 0.f, s2 = 0.f, s3 = 0.f;
#pragma unroll 8
    for (int f = 0; f < F_; f += 4) {      // 4 accumulators for ILP
        s0 += part[(size_t)f * B_ + b];
        s1 += part[(size_t)(f + 1) * B_ + b];
        s2 += part[(size_t)(f + 2) * B_ + b];
        s3 += part[(size_t)(f + 3) * B_ + b];
    }
    out[b] = (s0 + s1) + (s2 + s3) + bias[0];
}

extern "C" void kernel_launch(void* const* d_in, const int* in_sizes, int n_in,
                              void* d_out, int out_size, void* d_ws, size_t ws_size,
                              hipStream_t stream) {
    const float* x    = (const float*)d_in[0];
    const float* W1   = (const float*)d_in[1];
    const float* b1   = (const float*)d_in[2];
    const float* W2   = (const float*)d_in[3];
    const float* b2   = (const float*)d_in[4];
    const float* W3   = (const float*)d_in[5];
    const float* b3   = (const float*)d_in[6];
    const float* bias = (const float*)d_in[7];
    float* out  = (float*)d_out;
    float* part = (float*)d_ws;                         // 4 MB: [F][B] partials

    nam_main<<<F_ * NCHUNK, 256, 0, stream>>>(x, W1, b1, W2, b2, W3, b3, part);
    nam_reduce<<<B_ / 256, 256, 0, stream>>>(part, bias, out);
}